// Round 15
// baseline (85.899 us; speedup 1.0000x reference)
//
#include <hip/hip_runtime.h>
#include <stdint.h>

#define DCH 64
#define KC 512
#define HWSZ 4096
#define THETA 1e-4f
#define POSB 256      // positions per block (16 waves x 16)
#define BLOCK 1024
#define PADW 65       // rescue LDS row stride (floats): conflict-free

typedef __attribute__((ext_vector_type(8))) short short8v;
typedef __attribute__((ext_vector_type(4))) float floatx4;

// d_ws layout (bytes)
#define WS_WHS   0                        // 512*64 bf16 hi, SWIZZLED rows
#define WS_WLS   65536                    // 512*64 bf16 lo, SWIZZLED rows
#define WS_WNORM 131072                   // 512 f32 (numpy-pairwise exact)
#define WS_CNT   133120                   // int
#define WS_LIST  133184                   // up to 131072 int
#define WS_NEED  (133184 + 131072 * 4)

__device__ __forceinline__ uint16_t f2bf_rne(float x) {
  uint32_t u = __float_as_uint(x);
  uint32_t r = (u + 0x7fffu + ((u >> 16) & 1u)) >> 16;
  return (uint16_t)r;
}
__device__ __forceinline__ float bf2f(uint16_t b) {
  return __uint_as_float(((uint32_t)b) << 16);
}

// numpy pairwise_sum of squares, 64 elems (fp-contract off)
__device__ __forceinline__ float pairwise_sq64(const float* __restrict__ a) {
#pragma clang fp contract(off)
  float r0 = a[0]*a[0], r1 = a[1]*a[1], r2 = a[2]*a[2], r3 = a[3]*a[3];
  float r4 = a[4]*a[4], r5 = a[5]*a[5], r6 = a[6]*a[6], r7 = a[7]*a[7];
#pragma unroll
  for (int i = 8; i < 64; i += 8) {
    r0 += a[i+0]*a[i+0]; r1 += a[i+1]*a[i+1];
    r2 += a[i+2]*a[i+2]; r3 += a[i+3]*a[i+3];
    r4 += a[i+4]*a[i+4]; r5 += a[i+5]*a[i+5];
    r6 += a[i+6]*a[i+6]; r7 += a[i+7]*a[i+7];
  }
  return ((r0+r1)+(r2+r3)) + ((r4+r5)+(r6+r7));
}

// Load 8 Z elements (stride HWSZ), bf16-split element-wise.
__device__ __forceinline__ void load_frag(const float* __restrict__ p,
                                          short8v& vh, short8v& vl) {
#pragma unroll
  for (int j = 0; j < 8; ++j) {
    const float v = p[(size_t)j * HWSZ];
    const uint16_t hb = f2bf_rne(v);
    vh[j] = (short)hb;
    vl[j] = (short)f2bf_rne(v - bf2f(hb));
  }
}

// ---------- prep: W -> bf16 split (SWIZZLED image) + exact wnorm ----------
__global__ __launch_bounds__(64) void vq_prep(const float* __restrict__ W,
                                              char* __restrict__ ws) {
  const int c = blockIdx.x * 64 + threadIdx.x;   // 0..511
  const float* __restrict__ wr = W + c * DCH;
  float a[64];
#pragma unroll
  for (int i = 0; i < 16; ++i) {
    const float4 v = ((const float4*)wr)[i];
    a[4*i+0] = v.x; a[4*i+1] = v.y; a[4*i+2] = v.z; a[4*i+3] = v.w;
  }
  ((float*)(ws + WS_WNORM))[c] = pairwise_sq64(a);
  uint16_t* wh = (uint16_t*)(ws + WS_WHS);
  uint16_t* wl = (uint16_t*)(ws + WS_WLS);
#pragma unroll
  for (int gd = 0; gd < 8; ++gd) {
    short8v vh, vl;
#pragma unroll
    for (int e = 0; e < 8; ++e) {
      const float v = a[gd * 8 + e];
      const uint16_t hb = f2bf_rne(v);
      vh[e] = (short)hb;
      vl[e] = (short)f2bf_rne(v - bf2f(hb));
    }
    const int go = (gd ^ (c & 7)) << 3;   // swizzled granule slot
    *(short8v*)(wh + c * DCH + go) = vh;
    *(short8v*)(wl + c * DCH + go) = vl;
  }
  if (c == 0) *(int*)(ws + WS_CNT) = 0;
}

// ---------- main: MFMA scoring + top-2 gap test ----------
// R15: 1024 thr = 16 waves x 16 pos = 256 pos/block; grid 512 = 2 blocks/CU
// -> 8 waves/SIMD. LDS = two 32 KB quarter-buffers (double-buffered via
// global_load_lds prefetch) + wnorm. One barrier per quarter; the co-resident
// second block keeps the CU busy across barriers.
__global__ __launch_bounds__(BLOCK) void vq_main(const float* __restrict__ Z,
                                                 char* __restrict__ ws,
                                                 int* __restrict__ out) {
  __shared__ uint16_t buf0[16384];  // 32 KB: quarter hi [0,8192), lo [8192,16384)
  __shared__ uint16_t buf1[16384];  // 32 KB
  __shared__ float wnlds[KC];       // 2 KB

  const int tid = threadIdx.x;
  const int lane = tid & 63;
  const int wv = tid >> 6;                // 0..15
  const int csub = lane & 15;
  const int gsub = lane >> 4;
  const int nbase = blockIdx.x * POSB;

  const char* __restrict__ src_hi = (const char*)ws;            // 64 KB
  const char* __restrict__ src_lo = (const char*)ws + WS_WLS;   // 64 KB
  const float* __restrict__ wnorm = (const float*)(ws + WS_WNORM);
  int* cnt = (int*)(ws + WS_CNT);
  int* list = (int*)(ws + WS_LIST);

  // stage quarter q into dst (hi 16KB + lo 16KB); 1024 thr x 16 B = 16 KB/round
  auto STAGE = [&](int q, uint16_t* dst) {
    const int off = tid * 16;  // wv*1024 + lane*16: wave-uniform base + lane*16
    __builtin_amdgcn_global_load_lds((const uint32_t*)(src_hi + q * 16384 + off),
                                     (uint32_t*)((char*)dst + off), 16, 0, 0);
    __builtin_amdgcn_global_load_lds((const uint32_t*)(src_lo + q * 16384 + off),
                                     (uint32_t*)((char*)dst + 16384 + off), 16, 0, 0);
  };

  STAGE(0, buf0);
  if (tid < 128) {  // wnorm 2 KB via waves 0-1
    const int base = wv * 1024;
    __builtin_amdgcn_global_load_lds((const uint32_t*)((const char*)wnorm + base + lane * 16),
                                     (uint32_t*)((char*)wnlds + base), 16, 0, 0);
  }

  // A fragments: one 16-position set per wave (row = csub).
  short8v ah0, ah1, al0, al1;
  {
    const int b = nbase >> 12;
    const int hw0 = nbase & 4095;
    const float* zb = Z + (size_t)b * DCH * HWSZ + hw0 + wv * 16 + csub;
    const int dbase = gsub * 8;
    load_frag(zb + (size_t)(dbase +  0) * HWSZ, ah0, al0);
    load_frag(zb + (size_t)(dbase + 32) * HWSZ, ah1, al1);
  }

  float m1[4], m2[4];
  int i1[4];
#pragma unroll
  for (int r = 0; r < 4; ++r) { m1[r] = 3.4e38f; m2[r] = 3.4e38f; i1[r] = 0; }

  __syncthreads();  // quarter 0 + wnorm ready (vmcnt drained at barrier)

  // loop-invariant swizzle slots (row&7 == csub&7 within every quarter)
  const int go0 = (gsub ^ (csub & 7)) << 3;
  const int go1 = ((4 + gsub) ^ (csub & 7)) << 3;

#pragma unroll
  for (int q = 0; q < 4; ++q) {
    if (q < 3) STAGE(q + 1, (q & 1) ? buf0 : buf1);   // prefetch into idle buf
    const uint16_t* __restrict__ bh = (q & 1) ? buf1 : buf0;
    const uint16_t* __restrict__ bl = bh + 8192;
#pragma unroll
    for (int kt = 0; kt < 8; ++kt) {
      const int cq = kt * 16 + csub;          // row within quarter (0..127)
      const int cloc = q * 128 + cq;          // global code index
      const float wn = wnlds[cloc];
      const short8v bh0 = *(const short8v*)&bh[cq * DCH + go0];
      const short8v bh1 = *(const short8v*)&bh[cq * DCH + go1];
      const short8v bl0 = *(const short8v*)&bl[cq * DCH + go0];
      const short8v bl1 = *(const short8v*)&bl[cq * DCH + go1];
      const floatx4 zz = {0.f, 0.f, 0.f, 0.f};
      floatx4 c1 = __builtin_amdgcn_mfma_f32_16x16x32_bf16(ah0, bh0, zz, 0, 0, 0);
      floatx4 c2 = __builtin_amdgcn_mfma_f32_16x16x32_bf16(ah0, bl0, zz, 0, 0, 0);
      floatx4 c3 = __builtin_amdgcn_mfma_f32_16x16x32_bf16(al0, bh0, zz, 0, 0, 0);
      c1 = __builtin_amdgcn_mfma_f32_16x16x32_bf16(ah1, bh1, c1, 0, 0, 0);
      c2 = __builtin_amdgcn_mfma_f32_16x16x32_bf16(ah1, bl1, c2, 0, 0, 0);
      c3 = __builtin_amdgcn_mfma_f32_16x16x32_bf16(al1, bh1, c3, 0, 0, 0);
#pragma unroll
      for (int r = 0; r < 4; ++r) {
        const float s = fmaf(-2.0f, (c1[r] + c2[r]) + c3[r], wn);
        i1[r] = (s < m1[r]) ? cloc : i1[r];
        m2[r] = fminf(fmaxf(s, m1[r]), m2[r]);
        m1[r] = fminf(s, m1[r]);
      }
    }
    if (q < 3) __syncthreads();  // next quarter ready; readers of old buf done
  }

  // top-2 merge across the 16 lanes sharing each row group
#pragma unroll
  for (int off = 1; off < 16; off <<= 1) {
#pragma unroll
    for (int r = 0; r < 4; ++r) {
      const float om1 = __shfl_xor(m1[r], off, 64);
      const float om2 = __shfl_xor(m2[r], off, 64);
      const int oi = __shfl_xor(i1[r], off, 64);
      const float nm2 = fminf(fmaxf(m1[r], om1), fminf(m2[r], om2));
      i1[r] = (om1 < m1[r]) ? oi : i1[r];
      m1[r] = fminf(m1[r], om1);
      m2[r] = nm2;
    }
  }
  if (csub == 0) {
#pragma unroll
    for (int r = 0; r < 4; ++r) {
      const int pos = nbase + wv * 16 + gsub * 4 + r;
      out[pos] = i1[r];
      if (!(m2[r] - m1[r] > THETA)) {   // too close: exact re-score
        const int slot = atomicAdd(cnt, 1);
        list[slot] = pos;
      }
    }
  }
}

// ---------- rescue: LDS-staged W, conflict-free; bit-exact numpy order ----------
__global__ __launch_bounds__(256) void vq_rescue(const float* __restrict__ Z,
                                                 const float* __restrict__ W,
                                                 char* __restrict__ ws,
                                                 int* __restrict__ out) {
  __shared__ float wt[KC * PADW];   // 512 x 65 floats = 133,120 B
  const int cnt = *(const int*)(ws + WS_CNT);
  if (blockIdx.x * 4 >= cnt) return;   // block-uniform early out (before staging)

  const int lane = threadIdx.x & 63;
  const int wv = threadIdx.x >> 6;     // 0..3
  const int wvg = blockIdx.x * 4 + wv;
  const int* list = (const int*)(ws + WS_LIST);
  const float* wnorm = (const float*)(ws + WS_WNORM);

  for (int c = wv; c < KC; c += 4) {
    wt[c * PADW + lane] = W[c * DCH + lane];
  }
  __syncthreads();

  for (int j = wvg; j < cnt; j += 256 * 4) {
    const int pos = list[j];
    const int b = pos >> 12, hw = pos & 4095;
    float z[DCH];
    const float* zb = Z + ((size_t)b * DCH) * HWSZ + hw;
#pragma unroll
    for (int d = 0; d < DCH; ++d) z[d] = zb[(size_t)d * HWSZ];
    const float znorm = pairwise_sq64(z);
    float bm = 3.4e38f;
    int bi = 0;
#pragma unroll 1
    for (int j2 = 0; j2 < 8; ++j2) {
      const int k = j2 * 64 + lane;
      const float* __restrict__ wrow = &wt[k * PADW];  // lane-own row
      float acc = 0.f;
#pragma unroll
      for (int d = 0; d < DCH; ++d) acc = fmaf(z[d], wrow[d], acc);
      const float dist = (znorm - 2.0f * acc) + wnorm[k];
      if (dist < bm) { bm = dist; bi = k; }  // ascending k per lane
    }
#pragma unroll
    for (int off = 32; off >= 1; off >>= 1) {
      const float ov = __shfl_xor(bm, off, 64);
      const int oi = __shfl_xor(bi, off, 64);
      if (ov < bm || (ov == bm && oi < bi)) { bm = ov; bi = oi; }
    }
    if (lane == 0) out[pos] = bi;
  }
}

// ---------- fallback (R4, known exact) if ws too small ----------
__global__ __launch_bounds__(256, 4) void vq_fallback(const float* __restrict__ Z,
                                                      const float* __restrict__ W,
                                                      int* __restrict__ out) {
  __shared__ float wnorm[KC];
  __shared__ float cmin[4][64];
  __shared__ int cidx[4][64];
  const int tid = threadIdx.x;
  for (int c = tid; c < KC; c += 256) wnorm[c] = pairwise_sq64(W + c * DCH);
  const int lane = tid & 63;
  const int wv = __builtin_amdgcn_readfirstlane(tid >> 6);
  const int n = blockIdx.x * 64 + lane;
  float z[DCH];
  {
    const int b = n >> 12, hw = n & 4095;
    const float* zbase = Z + ((size_t)b * DCH) * HWSZ + hw;
#pragma unroll
    for (int d = 0; d < DCH; ++d) z[d] = zbase[(size_t)d * HWSZ];
  }
  const float znorm = pairwise_sq64(z);
  __syncthreads();
  float bmin = 3.4e38f;
  int bidx = 0;
  const int k0 = wv * 128;
#pragma unroll 1
  for (int kk = 0; kk < 128; kk += 8) {
    const int k = k0 + kk;
    const float* wr = W + (size_t)k * DCH;
    float acc[8];
#pragma unroll
    for (int j = 0; j < 8; ++j) acc[j] = 0.0f;
#pragma unroll
    for (int d = 0; d < DCH; ++d) {
      const float zd = z[d];
#pragma unroll
      for (int j = 0; j < 8; ++j) acc[j] = fmaf(zd, wr[j * DCH + d], acc[j]);
    }
#pragma unroll
    for (int j = 0; j < 8; ++j) {
      const float dist = (znorm - 2.0f * acc[j]) + wnorm[k + j];
      if (dist < bmin) { bmin = dist; bidx = k + j; }
    }
  }
  cmin[wv][lane] = bmin;
  cidx[wv][lane] = bidx;
  __syncthreads();
  if (tid < 64) {
    float m = cmin[0][tid];
    int ix = cidx[0][tid];
#pragma unroll
    for (int h = 1; h < 4; ++h) {
      if (cmin[h][tid] < m) { m = cmin[h][tid]; ix = cidx[h][tid]; }
    }
    out[blockIdx.x * 64 + tid] = ix;
  }
}

extern "C" void kernel_launch(void* const* d_in, const int* in_sizes, int n_in,
                              void* d_out, int out_size, void* d_ws, size_t ws_size,
                              hipStream_t stream) {
  const float* Z = (const float*)d_in[0];
  const float* W = (const float*)d_in[1];
  int* out = (int*)d_out;
  char* ws = (char*)d_ws;
  const int npos = in_sizes[0] / DCH;  // 131072

  if (ws_size < (size_t)WS_NEED) {
    vq_fallback<<<npos / 64, 256, 0, stream>>>(Z, W, out);
    return;
  }
  vq_prep<<<8, 64, 0, stream>>>(W, ws);
  vq_main<<<npos / POSB, BLOCK, 0, stream>>>(Z, ws, out);
  vq_rescue<<<256, 256, 0, stream>>>(Z, W, ws, out);
}

// Round 16
// 69.938 us; speedup vs baseline: 1.2282x; 1.2282x over previous
//
#include <hip/hip_runtime.h>
#include <stdint.h>

#define DCH 64
#define KC 512
#define HWSZ 4096
#define THETA 1e-4f
#define POSB 512      // positions per block (16 waves x 32)
#define BLOCK 1024
#define PADW 65       // rescue LDS row stride (floats): conflict-free

typedef __attribute__((ext_vector_type(8))) short short8v;
typedef __attribute__((ext_vector_type(4))) float floatx4;

// d_ws layout (bytes)
#define WS_WHS   0                        // 512*64 bf16 hi, SWIZZLED rows
#define WS_WLS   65536                    // 512*64 bf16 lo, SWIZZLED rows
#define WS_WNORM 131072                   // 512 f32 (numpy-pairwise exact)
#define WS_CNT   133120                   // int
#define WS_LIST  133184                   // up to 131072 int
#define WS_NEED  (133184 + 131072 * 4)

__device__ __forceinline__ uint16_t f2bf_rne(float x) {
  uint32_t u = __float_as_uint(x);
  uint32_t r = (u + 0x7fffu + ((u >> 16) & 1u)) >> 16;
  return (uint16_t)r;
}
__device__ __forceinline__ float bf2f(uint16_t b) {
  return __uint_as_float(((uint32_t)b) << 16);
}

// numpy pairwise_sum of squares, 64 elems (fp-contract off)
__device__ __forceinline__ float pairwise_sq64(const float* __restrict__ a) {
#pragma clang fp contract(off)
  float r0 = a[0]*a[0], r1 = a[1]*a[1], r2 = a[2]*a[2], r3 = a[3]*a[3];
  float r4 = a[4]*a[4], r5 = a[5]*a[5], r6 = a[6]*a[6], r7 = a[7]*a[7];
#pragma unroll
  for (int i = 8; i < 64; i += 8) {
    r0 += a[i+0]*a[i+0]; r1 += a[i+1]*a[i+1];
    r2 += a[i+2]*a[i+2]; r3 += a[i+3]*a[i+3];
    r4 += a[i+4]*a[i+4]; r5 += a[i+5]*a[i+5];
    r6 += a[i+6]*a[i+6]; r7 += a[i+7]*a[i+7];
  }
  return ((r0+r1)+(r2+r3)) + ((r4+r5)+(r6+r7));
}

// Load 8 Z elements (stride HWSZ), bf16-split element-wise.
__device__ __forceinline__ void load_frag(const float* __restrict__ p,
                                          short8v& vh, short8v& vl) {
#pragma unroll
  for (int j = 0; j < 8; ++j) {
    const float v = p[(size_t)j * HWSZ];
    const uint16_t hb = f2bf_rne(v);
    vh[j] = (short)hb;
    vl[j] = (short)f2bf_rne(v - bf2f(hb));
  }
}

// ---------- prep: W -> bf16 split (SWIZZLED image) + exact wnorm ----------
__global__ __launch_bounds__(64) void vq_prep(const float* __restrict__ W,
                                              char* __restrict__ ws) {
  const int c = blockIdx.x * 64 + threadIdx.x;   // 0..511
  const float* __restrict__ wr = W + c * DCH;
  float a[64];
#pragma unroll
  for (int i = 0; i < 16; ++i) {
    const float4 v = ((const float4*)wr)[i];
    a[4*i+0] = v.x; a[4*i+1] = v.y; a[4*i+2] = v.z; a[4*i+3] = v.w;
  }
  ((float*)(ws + WS_WNORM))[c] = pairwise_sq64(a);
  uint16_t* wh = (uint16_t*)(ws + WS_WHS);
  uint16_t* wl = (uint16_t*)(ws + WS_WLS);
#pragma unroll
  for (int gd = 0; gd < 8; ++gd) {
    short8v vh, vl;
#pragma unroll
    for (int e = 0; e < 8; ++e) {
      const float v = a[gd * 8 + e];
      const uint16_t hb = f2bf_rne(v);
      vh[e] = (short)hb;
      vl[e] = (short)f2bf_rne(v - bf2f(hb));
    }
    const int go = (gd ^ (c & 7)) << 3;   // swizzled granule slot
    *(short8v*)(wh + c * DCH + go) = vh;
    *(short8v*)(wl + c * DCH + go) = vl;
  }
  if (c == 0) *(int*)(ws + WS_CNT) = 0;
}

// ---------- main: MFMA scoring + top-2 gap test ----------
// 1024 threads = 16 waves x 32 positions; grid = 256 = 1 block/CU.
// Whole 128 KB split-W image in LDS once, single barrier, barrier-free loop.
// R16 = R12 (best-known, 69.7 us total) + s_setprio around the MFMA cluster.
__global__ __launch_bounds__(BLOCK) void vq_main(const float* __restrict__ Z,
                                                 char* __restrict__ ws,
                                                 int* __restrict__ out) {
  __shared__ uint16_t img[65536];   // 128 KB: hi [0,32768), lo [32768,65536)
  __shared__ float wnlds[KC];       // 2 KB

  const int tid = threadIdx.x;
  const int lane = tid & 63;
  const int wv = tid >> 6;                // 0..15
  const int csub = lane & 15;
  const int gsub = lane >> 4;
  const int nbase = blockIdx.x * POSB;

  const char* __restrict__ img_src = (const char*)ws;  // 128 KB contiguous
  const float* __restrict__ wnorm = (const float*)(ws + WS_WNORM);
  int* cnt = (int*)(ws + WS_CNT);
  int* list = (int*)(ws + WS_LIST);

#pragma unroll
  for (int r = 0; r < 8; ++r) {
    const int base = r * 16384 + wv * 1024;   // wave-uniform LDS byte base
    __builtin_amdgcn_global_load_lds((const uint32_t*)(img_src + base + lane * 16),
                                     (uint32_t*)((char*)img + base), 16, 0, 0);
  }
  if (tid < 128) {
    const int base = wv * 1024;
    __builtin_amdgcn_global_load_lds((const uint32_t*)((const char*)wnorm + base + lane * 16),
                                     (uint32_t*)((char*)wnlds + base), 16, 0, 0);
  }

  short8v ahA0, ahA1, alA0, alA1, ahB0, ahB1, alB0, alB1;
  {
    const int b = nbase >> 12;
    const int hw0 = nbase & 4095;
    const float* zb = Z + (size_t)b * DCH * HWSZ + hw0 + wv * 32 + csub;
    const int dbase = gsub * 8;
    load_frag(zb + (size_t)(dbase +  0) * HWSZ,      ahA0, alA0);
    load_frag(zb + (size_t)(dbase + 32) * HWSZ,      ahA1, alA1);
    load_frag(zb + (size_t)(dbase +  0) * HWSZ + 16, ahB0, alB0);
    load_frag(zb + (size_t)(dbase + 32) * HWSZ + 16, ahB1, alB1);
  }

  float m1A[4], m2A[4], m1B[4], m2B[4];
  int i1A[4], i1B[4];
#pragma unroll
  for (int r = 0; r < 4; ++r) {
    m1A[r] = 3.4e38f; m2A[r] = 3.4e38f; i1A[r] = 0;
    m1B[r] = 3.4e38f; m2B[r] = 3.4e38f; i1B[r] = 0;
  }

  __syncthreads();  // image + wnorm ready; ONLY barrier.

  const uint16_t* __restrict__ whl = img;            // hi
  const uint16_t* __restrict__ wll = img + 32768;    // lo

  // loop-invariant swizzle slots (cloc&7 == csub&7 since kt*16 % 8 == 0)
  const int go0 = (gsub ^ (csub & 7)) << 3;
  const int go1 = ((4 + gsub) ^ (csub & 7)) << 3;

#pragma unroll 8
  for (int kt = 0; kt < KC / 16; ++kt) {
    const int cloc = kt * 16 + csub;
    const float wn = wnlds[cloc];
    const short8v bh0 = *(const short8v*)&whl[cloc * DCH + go0];
    const short8v bh1 = *(const short8v*)&whl[cloc * DCH + go1];
    const short8v bl0 = *(const short8v*)&wll[cloc * DCH + go0];
    const short8v bl1 = *(const short8v*)&wll[cloc * DCH + go1];
    const floatx4 zz = {0.f, 0.f, 0.f, 0.f};
    // T5: boost wave priority while the matrix pipe is fed (waves here are
    // barrier-free and slip freely, the regime where setprio paid on attn).
    __builtin_amdgcn_s_setprio(1);
    floatx4 cA1 = __builtin_amdgcn_mfma_f32_16x16x32_bf16(ahA0, bh0, zz, 0, 0, 0);
    floatx4 cB1 = __builtin_amdgcn_mfma_f32_16x16x32_bf16(ahB0, bh0, zz, 0, 0, 0);
    floatx4 cA2 = __builtin_amdgcn_mfma_f32_16x16x32_bf16(ahA0, bl0, zz, 0, 0, 0);
    floatx4 cB2 = __builtin_amdgcn_mfma_f32_16x16x32_bf16(ahB0, bl0, zz, 0, 0, 0);
    floatx4 cA3 = __builtin_amdgcn_mfma_f32_16x16x32_bf16(alA0, bh0, zz, 0, 0, 0);
    floatx4 cB3 = __builtin_amdgcn_mfma_f32_16x16x32_bf16(alB0, bh0, zz, 0, 0, 0);
    cA1 = __builtin_amdgcn_mfma_f32_16x16x32_bf16(ahA1, bh1, cA1, 0, 0, 0);
    cB1 = __builtin_amdgcn_mfma_f32_16x16x32_bf16(ahB1, bh1, cB1, 0, 0, 0);
    cA2 = __builtin_amdgcn_mfma_f32_16x16x32_bf16(ahA1, bl1, cA2, 0, 0, 0);
    cB2 = __builtin_amdgcn_mfma_f32_16x16x32_bf16(ahB1, bl1, cB2, 0, 0, 0);
    cA3 = __builtin_amdgcn_mfma_f32_16x16x32_bf16(alA1, bh1, cA3, 0, 0, 0);
    cB3 = __builtin_amdgcn_mfma_f32_16x16x32_bf16(alB1, bh1, cB3, 0, 0, 0);
    __builtin_amdgcn_s_setprio(0);
#pragma unroll
    for (int r = 0; r < 4; ++r) {
      const float sA = fmaf(-2.0f, (cA1[r] + cA2[r]) + cA3[r], wn);
      i1A[r] = (sA < m1A[r]) ? cloc : i1A[r];
      m2A[r] = fminf(fmaxf(sA, m1A[r]), m2A[r]);
      m1A[r] = fminf(sA, m1A[r]);
      const float sB = fmaf(-2.0f, (cB1[r] + cB2[r]) + cB3[r], wn);
      i1B[r] = (sB < m1B[r]) ? cloc : i1B[r];
      m2B[r] = fminf(fmaxf(sB, m1B[r]), m2B[r]);
      m1B[r] = fminf(sB, m1B[r]);
    }
  }

#pragma unroll
  for (int off = 1; off < 16; off <<= 1) {
#pragma unroll
    for (int r = 0; r < 4; ++r) {
      {
        const float om1 = __shfl_xor(m1A[r], off, 64);
        const float om2 = __shfl_xor(m2A[r], off, 64);
        const int oi = __shfl_xor(i1A[r], off, 64);
        const float nm2 = fminf(fmaxf(m1A[r], om1), fminf(m2A[r], om2));
        i1A[r] = (om1 < m1A[r]) ? oi : i1A[r];
        m1A[r] = fminf(m1A[r], om1);
        m2A[r] = nm2;
      }
      {
        const float om1 = __shfl_xor(m1B[r], off, 64);
        const float om2 = __shfl_xor(m2B[r], off, 64);
        const int oi = __shfl_xor(i1B[r], off, 64);
        const float nm2 = fminf(fmaxf(m1B[r], om1), fminf(m2B[r], om2));
        i1B[r] = (om1 < m1B[r]) ? oi : i1B[r];
        m1B[r] = fminf(m1B[r], om1);
        m2B[r] = nm2;
      }
    }
  }
  if (csub == 0) {
#pragma unroll
    for (int r = 0; r < 4; ++r) {
      const int posA = nbase + wv * 32 + gsub * 4 + r;
      out[posA] = i1A[r];
      if (!(m2A[r] - m1A[r] > THETA)) {
        const int slot = atomicAdd(cnt, 1);
        list[slot] = posA;
      }
      const int posB = posA + 16;
      out[posB] = i1B[r];
      if (!(m2B[r] - m1B[r] > THETA)) {
        const int slot = atomicAdd(cnt, 1);
        list[slot] = posB;
      }
    }
  }
}

// ---------- rescue: LDS-staged W, conflict-free; bit-exact numpy order ----------
__global__ __launch_bounds__(256) void vq_rescue(const float* __restrict__ Z,
                                                 const float* __restrict__ W,
                                                 char* __restrict__ ws,
                                                 int* __restrict__ out) {
  __shared__ float wt[KC * PADW];   // 512 x 65 floats = 133,120 B
  const int cnt = *(const int*)(ws + WS_CNT);
  if (blockIdx.x * 4 >= cnt) return;   // block-uniform early out (before staging)

  const int lane = threadIdx.x & 63;
  const int wv = threadIdx.x >> 6;     // 0..3
  const int wvg = blockIdx.x * 4 + wv;
  const int* list = (const int*)(ws + WS_LIST);
  const float* wnorm = (const float*)(ws + WS_WNORM);

  for (int c = wv; c < KC; c += 4) {
    wt[c * PADW + lane] = W[c * DCH + lane];
  }
  __syncthreads();

  for (int j = wvg; j < cnt; j += 256 * 4) {
    const int pos = list[j];
    const int b = pos >> 12, hw = pos & 4095;
    float z[DCH];
    const float* zb = Z + ((size_t)b * DCH) * HWSZ + hw;
#pragma unroll
    for (int d = 0; d < DCH; ++d) z[d] = zb[(size_t)d * HWSZ];
    const float znorm = pairwise_sq64(z);
    float bm = 3.4e38f;
    int bi = 0;
#pragma unroll 1
    for (int j2 = 0; j2 < 8; ++j2) {
      const int k = j2 * 64 + lane;
      const float* __restrict__ wrow = &wt[k * PADW];  // lane-own row
      float acc = 0.f;
#pragma unroll
      for (int d = 0; d < DCH; ++d) acc = fmaf(z[d], wrow[d], acc);
      const float dist = (znorm - 2.0f * acc) + wnorm[k];
      if (dist < bm) { bm = dist; bi = k; }  // ascending k per lane
    }
#pragma unroll
    for (int off = 32; off >= 1; off >>= 1) {
      const float ov = __shfl_xor(bm, off, 64);
      const int oi = __shfl_xor(bi, off, 64);
      if (ov < bm || (ov == bm && oi < bi)) { bm = ov; bi = oi; }
    }
    if (lane == 0) out[pos] = bi;
  }
}

// ---------- fallback (R4, known exact) if ws too small ----------
__global__ __launch_bounds__(256, 4) void vq_fallback(const float* __restrict__ Z,
                                                      const float* __restrict__ W,
                                                      int* __restrict__ out) {
  __shared__ float wnorm[KC];
  __shared__ float cmin[4][64];
  __shared__ int cidx[4][64];
  const int tid = threadIdx.x;
  for (int c = tid; c < KC; c += 256) wnorm[c] = pairwise_sq64(W + c * DCH);
  const int lane = tid & 63;
  const int wv = __builtin_amdgcn_readfirstlane(tid >> 6);
  const int n = blockIdx.x * 64 + lane;
  float z[DCH];
  {
    const int b = n >> 12, hw = n & 4095;
    const float* zbase = Z + ((size_t)b * DCH) * HWSZ + hw;
#pragma unroll
    for (int d = 0; d < DCH; ++d) z[d] = zbase[(size_t)d * HWSZ];
  }
  const float znorm = pairwise_sq64(z);
  __syncthreads();
  float bmin = 3.4e38f;
  int bidx = 0;
  const int k0 = wv * 128;
#pragma unroll 1
  for (int kk = 0; kk < 128; kk += 8) {
    const int k = k0 + kk;
    const float* wr = W + (size_t)k * DCH;
    float acc[8];
#pragma unroll
    for (int j = 0; j < 8; ++j) acc[j] = 0.0f;
#pragma unroll
    for (int d = 0; d < DCH; ++d) {
      const float zd = z[d];
#pragma unroll
      for (int j = 0; j < 8; ++j) acc[j] = fmaf(zd, wr[j * DCH + d], acc[j]);
    }
#pragma unroll
    for (int j = 0; j < 8; ++j) {
      const float dist = (znorm - 2.0f * acc[j]) + wnorm[k + j];
      if (dist < bmin) { bmin = dist; bidx = k + j; }
    }
  }
  cmin[wv][lane] = bmin;
  cidx[wv][lane] = bidx;
  __syncthreads();
  if (tid < 64) {
    float m = cmin[0][tid];
    int ix = cidx[0][tid];
#pragma unroll
    for (int h = 1; h < 4; ++h) {
      if (cmin[h][tid] < m) { m = cmin[h][tid]; ix = cidx[h][tid]; }
    }
    out[blockIdx.x * 64 + tid] = ix;
  }
}

extern "C" void kernel_launch(void* const* d_in, const int* in_sizes, int n_in,
                              void* d_out, int out_size, void* d_ws, size_t ws_size,
                              hipStream_t stream) {
  const float* Z = (const float*)d_in[0];
  const float* W = (const float*)d_in[1];
  int* out = (int*)d_out;
  char* ws = (char*)d_ws;
  const int npos = in_sizes[0] / DCH;  // 131072

  if (ws_size < (size_t)WS_NEED) {
    vq_fallback<<<npos / 64, 256, 0, stream>>>(Z, W, out);
    return;
  }
  vq_prep<<<8, 64, 0, stream>>>(W, ws);
  vq_main<<<npos / POSB, BLOCK, 0, stream>>>(Z, ws, out);
  vq_rescue<<<256, 256, 0, stream>>>(Z, W, ws, out);
}